// Round 4
// baseline (714.017 us; speedup 1.0000x reference)
//
#include <hip/hip_runtime.h>

#define DEV __device__ __forceinline__

typedef short bf16x8 __attribute__((ext_vector_type(8)));
typedef float f32x4 __attribute__((ext_vector_type(4)));
typedef float f32x16 __attribute__((ext_vector_type(16)));
typedef unsigned short u16;
typedef unsigned int u32;

typedef __attribute__((address_space(3))) void lds_void;
typedef __attribute__((address_space(1))) void gbl_void;

DEV void async_copy16(void* lds_dst, const void* g_src) {
    __builtin_amdgcn_global_load_lds((gbl_void*)g_src, (lds_void*)lds_dst, 16, 0, 0);
}

DEV u16 f2bf(float x) {
    u32 u = __float_as_uint(x);
    return (u16)((u + 0x7fffu + ((u >> 16) & 1u)) >> 16);
}
DEV u16 f2bf_fast(float x) {  // x >= 0, finite
    return (u16)((__float_as_uint(x) + 0x8000u) >> 16);
}
DEV float bf2f(u16 v) { return __uint_as_float(((u32)v) << 16); }

// ---------------------------------------------------------------------------
// fp32 -> bf16 conversion (vectorized by 4)
// ---------------------------------------------------------------------------
__global__ __launch_bounds__(256) void f2bf_kernel(const float* __restrict__ src,
                                                   u16* __restrict__ dst, int n4) {
    const int i = blockIdx.x * 256 + threadIdx.x;
    if (i < n4) {
        const float4 v = ((const float4*)src)[i];
        ushort4 o;
        o.x = f2bf(v.x); o.y = f2bf(v.y); o.z = f2bf(v.z); o.w = f2bf(v.w);
        ((ushort4*)dst)[i] = o;
    }
}

// ---------------------------------------------------------------------------
// Span scatter: RoPE row -> gate dot -> atomicAdd coef*tag_emb into out_pre
// ---------------------------------------------------------------------------
__global__ __launch_bounds__(256) void span_kernel(
    const float* __restrict__ we, const int* __restrict__ sb,
    const int* __restrict__ ss, const int* __restrict__ stg,
    const float* __restrict__ tag_emb, const float* __restrict__ gate_w,
    const float* __restrict__ gate_b, float* __restrict__ out_pre) {
    __shared__ float red[4];
    const int n = blockIdx.x >> 5;
    const int l = blockIdx.x & 31;
    const int t = threadIdx.x;
    const int b = sb[n];
    const int s = ss[n] + l;
    const int tag = stg[n];
    const long base = ((long)b * 1024 + s) * 1024;
    float dot = 0.f;
#pragma unroll
    for (int pp = 0; pp < 2; ++pp) {
        const int p = t + pp * 256;
        const float e1 = we[base + 2 * p];
        const float e2 = we[base + 2 * p + 1];
        const float inv = exp2f((float)p * (-13.287712379549449f / 512.0f));
        const float ang = (float)s * inv;
        const float sa = sinf(ang), ca = cosf(ang);
        const float r1 = e1 * ca - e2 * sa;
        const float r2 = e1 * sa + e2 * ca;
        dot += r1 * gate_w[2 * p] + r2 * gate_w[2 * p + 1];
    }
#pragma unroll
    for (int off = 32; off > 0; off >>= 1) dot += __shfl_xor(dot, off, 64);
    if ((t & 63) == 0) red[t >> 6] = dot;
    __syncthreads();
    const float z = red[0] + red[1] + red[2] + red[3] + gate_b[0];
    const float gate = 0.25f + 0.5f / (1.f + __expf(-z));
    const float coef = gate * 16.f;
    const float* te = tag_emb + (long)tag * 1024;
#pragma unroll
    for (int c = 0; c < 4; ++c) {
        const int d = t + c * 256;
        atomicAdd(&out_pre[base + d], coef * te[d]);
    }
}

// ---------------------------------------------------------------------------
// LayerNorm over D=1024, one block per row.
// ---------------------------------------------------------------------------
template <bool WRITE_F32, bool WRITE_BF, bool FINAL>
__global__ __launch_bounds__(256) void ln_kernel(
    const float* __restrict__ X, const float* __restrict__ g,
    const float* __restrict__ bta, float eps, float* __restrict__ Yf,
    u16* __restrict__ Ybf, const u16* __restrict__ addend) {
    __shared__ float red[8];
    const long row = blockIdx.x;
    const int t = threadIdx.x;
    const float4 x = ((const float4*)(X + row * 1024))[t];
    float s = x.x + x.y + x.z + x.w;
#pragma unroll
    for (int off = 32; off > 0; off >>= 1) s += __shfl_xor(s, off, 64);
    if ((t & 63) == 0) red[t >> 6] = s;
    __syncthreads();
    const float mean = (red[0] + red[1] + red[2] + red[3]) * (1.f / 1024.f);
    float4 dx;
    dx.x = x.x - mean; dx.y = x.y - mean; dx.z = x.z - mean; dx.w = x.w - mean;
    float ss = dx.x * dx.x + dx.y * dx.y + dx.z * dx.z + dx.w * dx.w;
#pragma unroll
    for (int off = 32; off > 0; off >>= 1) ss += __shfl_xor(ss, off, 64);
    if ((t & 63) == 0) red[4 + (t >> 6)] = ss;
    __syncthreads();
    const float var = (red[4] + red[5] + red[6] + red[7]) * (1.f / 1024.f);
    const float rstd = rsqrtf(var + eps);
    const float4 gv = ((const float4*)g)[t];
    const float4 bv = ((const float4*)bta)[t];
    float4 y;
    y.x = dx.x * rstd * gv.x + bv.x;
    y.y = dx.y * rstd * gv.y + bv.y;
    y.z = dx.z * rstd * gv.z + bv.z;
    y.w = dx.w * rstd * gv.w + bv.w;
    if (FINAL) {
        const ushort4 a = ((const ushort4*)(addend + row * 1024))[t];
        y.x += bf2f(a.x); y.y += bf2f(a.y); y.z += bf2f(a.z); y.w += bf2f(a.w);
    }
    if (WRITE_F32) ((float4*)(Yf + row * 1024))[t] = y;
    if (WRITE_BF) {
        ushort4 o;
        o.x = f2bf(y.x); o.y = f2bf(y.y); o.z = f2bf(y.z); o.w = f2bf(y.w);
        ((ushort4*)(Ybf + row * 1024))[t] = o;
    }
}

// ---------------------------------------------------------------------------
// NT GEMM v2: C[M,N] = A[M,K] @ B[N,K]^T + bias, optional ReLU / bf16 res.
// 128x128 block tile, 4 waves (2x2 of 64x64), each wave 2x2 of 32x32 MFMAs
// (v_mfma_f32_32x32x16_bf16). BK=64. LDS staged via global_load_lds in
// FRAGMENT-CONTIGUOUS order: chunk C = rg*256 + kstep*64 + lane holds
// X[row = 32*rg + (lane&31)][k = 16*kstep + 8*(lane>>5) ..+8], so every
// fragment read is one contiguous 1KB/wave ds_read_b128 (conflict-free).
// ---------------------------------------------------------------------------
template <bool OUT_BF16, bool RELU, bool HAS_RES>
__global__ __launch_bounds__(256, 2) void gemm_nt(
    const u16* __restrict__ A, const u16* __restrict__ B,
    const float* __restrict__ bias, const u16* __restrict__ res,
    void* __restrict__ Cout, int N, int K) {
    __shared__ u16 Al[8192];   // 16 KB
    __shared__ u16 Bl[8192];   // 16 KB
    const int tid = threadIdx.x;
    const int wave = tid >> 6;
    const int lane = tid & 63;
    const int l31 = lane & 31;
    const int half = lane >> 5;
    const int wm = wave >> 1;
    const int wn = wave & 1;
    const long rowBase = (long)blockIdx.x * 128;
    const long colBase = (long)blockIdx.y * 128;

    f32x16 acc[2][2];
#pragma unroll
    for (int i = 0; i < 2; ++i)
#pragma unroll
        for (int j = 0; j < 2; ++j)
#pragma unroll
            for (int r = 0; r < 16; ++r) acc[i][j][r] = 0.f;

    // staging: call c stages rows [32c, 32c+32) x 64 k; thread loads
    // g[(32c + (tid&31))*K + 16*(tid>>6) + 8*((tid>>5)&1)]
    const int srow = tid & 31;
    const int skoff = (tid >> 6) * 16 + ((tid >> 5) & 1) * 8;
    const u16* gA = A + (rowBase + srow) * (long)K + skoff;
    const u16* gB = B + (colBase + srow) * (long)K + skoff;

    for (int kt = 0; kt < K; kt += 64) {
        __syncthreads();
#pragma unroll
        for (int c = 0; c < 4; ++c) {
            async_copy16(Al + c * 2048 + wave * 512, gA + (long)c * 32 * K + kt);
            async_copy16(Bl + c * 2048 + wave * 512, gB + (long)c * 32 * K + kt);
        }
        __syncthreads();
#pragma unroll
        for (int ks = 0; ks < 4; ++ks) {
            bf16x8 af[2], bfr[2];
#pragma unroll
            for (int i = 0; i < 2; ++i)
                af[i] = *(const bf16x8*)&Al[((wm * 2 + i) * 256 + ks * 64 + lane) * 8];
#pragma unroll
            for (int j = 0; j < 2; ++j)
                bfr[j] = *(const bf16x8*)&Bl[((wn * 2 + j) * 256 + ks * 64 + lane) * 8];
#pragma unroll
            for (int i = 0; i < 2; ++i)
#pragma unroll
                for (int j = 0; j < 2; ++j)
                    acc[i][j] = __builtin_amdgcn_mfma_f32_32x32x16_bf16(
                        af[i], bfr[j], acc[i][j], 0, 0, 0);
        }
    }

    // epilogue: C/D layout col=lane&31, row=(r&3)+8*(r>>2)+4*half
    float biasv[2];
#pragma unroll
    for (int j = 0; j < 2; ++j) biasv[j] = bias[colBase + wn * 64 + j * 32 + l31];
#pragma unroll
    for (int i = 0; i < 2; ++i) {
        const long rb = rowBase + wm * 64 + i * 32 + 4 * half;
#pragma unroll
        for (int j = 0; j < 2; ++j) {
            const long gcol = colBase + wn * 64 + j * 32 + l31;
#pragma unroll
            for (int r = 0; r < 16; ++r) {
                const long grow = rb + (r & 3) + 8 * (r >> 2);
                float v = acc[i][j][r] + biasv[j];
                if (RELU) v = fmaxf(v, 0.f);
                if (HAS_RES) v += bf2f(res[grow * N + gcol]);
                if (OUT_BF16)
                    ((u16*)Cout)[grow * N + gcol] = f2bf(v);
                else
                    ((float*)Cout)[grow * N + gcol] = v;
            }
        }
    }
}

// ---------------------------------------------------------------------------
// V transpose: Vt[b,h,d,s] (bf16) <- QKV[(b*S+s)*3072 + 2048 + h*64 + d]
// ---------------------------------------------------------------------------
__global__ __launch_bounds__(256) void vtrans_kernel(const u16* __restrict__ QKV,
                                                     u16* __restrict__ Vt) {
    __shared__ u16 tile[64][72];
    const int bid = blockIdx.x;
    const int st = bid & 15;
    const int h = (bid >> 4) & 15;
    const int b = bid >> 8;
    const int t = threadIdx.x;
    const int sl = t >> 2;
    const int dc = (t & 3) * 16;
    const u16* src = QKV + ((long)(b * 1024 + st * 64 + sl)) * 3072 + 2048 + h * 64 + dc;
    *(uint4*)&tile[sl][dc] = *(const uint4*)src;
    *(uint4*)&tile[sl][dc + 8] = *(const uint4*)(src + 8);
    __syncthreads();
    const int dl = t >> 2;
    const int sc = (t & 3) * 16;
    union { u16 u[16]; uint4 q[2]; } tmp;
#pragma unroll
    for (int i = 0; i < 16; ++i) tmp.u[i] = tile[sc + i][dl];
    u16* dst = Vt + ((long)(b * 16 + h) * 64 + dl) * 1024 + st * 64 + sc;
    *(uint4*)dst = tmp.q[0];
    *(uint4*)(dst + 8) = tmp.q[1];
}

// ---------------------------------------------------------------------------
// Flash attention (round-3 version, unchanged).
// ---------------------------------------------------------------------------
__global__ __launch_bounds__(256, 4) void attn_kernel(
    const u16* __restrict__ QKV, const u16* __restrict__ Vt,
    const int* __restrict__ mask, u16* __restrict__ Out) {
    __shared__ u16 KL[4096];
    __shared__ u16 VL[4096];
    __shared__ u16 PL[4][16 * 72];
    const int tid = threadIdx.x;
    const int wid = tid >> 6;
    const int lane = tid & 63;
    const int quad = lane >> 4;
    const int lq = lane & 15;
    const int slot0 = quad ^ (lq & 7);
    const int slot1 = slot0 ^ 4;

    const int bid = blockIdx.x;
    const int qb = bid & 7;
    const int h = (bid >> 3) & 15;
    const int b = bid >> 7;
    const int qbase = qb * 128 + wid * 32;

    bf16x8 aq[2][2];
#pragma unroll
    for (int t = 0; t < 2; ++t) {
        const u16* qp = QKV + ((long)(b * 1024 + qbase + t * 16 + lq)) * 3072 +
                        h * 64 + quad * 8;
        aq[t][0] = *(const bf16x8*)qp;
        aq[t][1] = *(const bf16x8*)(qp + 32);
    }

    const int c0 = tid, c1 = 256 + tid;
    const int r0 = c0 >> 3, j0 = (c0 & 7) ^ (r0 & 7);
    const int r1 = c1 >> 3, j1 = (c1 & 7) ^ (r1 & 7);
    const u16* srcK0 = QKV + ((long)(b * 1024 + r0)) * 3072 + 1024 + h * 64 + j0 * 8;
    const u16* srcK1 = QKV + ((long)(b * 1024 + r1)) * 3072 + 1024 + h * 64 + j1 * 8;
    const u16* srcV0 = Vt + ((long)(b * 16 + h) * 64 + r0) * 1024 + j0 * 8;
    const u16* srcV1 = Vt + ((long)(b * 16 + h) * 64 + r1) * 1024 + j1 * 8;
    u16* ldsK0 = KL + wid * 512;
    u16* ldsK1 = KL + 2048 + wid * 512;
    u16* ldsV0 = VL + wid * 512;
    u16* ldsV1 = VL + 2048 + wid * 512;

    const f32x4 fzero = {0.f, 0.f, 0.f, 0.f};
    f32x4 acc[2][4];
#pragma unroll
    for (int t = 0; t < 2; ++t)
#pragma unroll
        for (int j = 0; j < 4; ++j) acc[t][j] = fzero;
    float lsum[2][4] = {{0.f, 0.f, 0.f, 0.f}, {0.f, 0.f, 0.f, 0.f}};
    u16* myP = PL[wid];
    const int* mrow = mask + b * 1024;

    for (int kt = 0; kt < 1024; kt += 64) {
        __syncthreads();
        async_copy16(ldsK0, srcK0 + (long)kt * 3072);
        async_copy16(ldsK1, srcK1 + (long)kt * 3072);
        async_copy16(ldsV0, srcV0 + kt);
        async_copy16(ldsV1, srcV1 + kt);
        __syncthreads();

        bf16x8 kf0[4], kf1[4];
#pragma unroll
        for (int ct = 0; ct < 4; ++ct) {
            const int rowb = (ct * 16 + lq) * 64;
            kf0[ct] = *(const bf16x8*)&KL[rowb + slot0 * 8];
            kf1[ct] = *(const bf16x8*)&KL[rowb + slot1 * 8];
        }
        float mw[4];
#pragma unroll
        for (int ct = 0; ct < 4; ++ct) mw[ct] = mrow[kt + ct * 16 + lq] ? 1.f : 0.f;

#pragma unroll
        for (int t = 0; t < 2; ++t) {
            f32x4 s[4];
#pragma unroll
            for (int ct = 0; ct < 4; ++ct) {
                s[ct] = __builtin_amdgcn_mfma_f32_16x16x32_bf16(aq[t][0], kf0[ct],
                                                                fzero, 0, 0, 0);
                s[ct] = __builtin_amdgcn_mfma_f32_16x16x32_bf16(aq[t][1], kf1[ct],
                                                                s[ct], 0, 0, 0);
            }
            asm volatile("s_waitcnt lgkmcnt(0)" ::: "memory");
#pragma unroll
            for (int ct = 0; ct < 4; ++ct)
#pragma unroll
                for (int r = 0; r < 4; ++r) {
                    const float p = mw[ct] * __expf(s[ct][r] * 0.125f);
                    lsum[t][r] += p;
                    myP[(quad * 4 + r) * 72 + ct * 16 + lq] = f2bf_fast(p);
                }
            asm volatile("s_waitcnt lgkmcnt(0)" ::: "memory");
            const bf16x8 pf0 = *(const bf16x8*)&myP[lq * 72 + quad * 8];
            const bf16x8 pf1 = *(const bf16x8*)&myP[lq * 72 + 32 + quad * 8];
#pragma unroll
            for (int j = 0; j < 4; ++j) {
                const int rowb = (j * 16 + lq) * 64;
                const bf16x8 vf0 = *(const bf16x8*)&VL[rowb + slot0 * 8];
                const bf16x8 vf1 = *(const bf16x8*)&VL[rowb + slot1 * 8];
                acc[t][j] = __builtin_amdgcn_mfma_f32_16x16x32_bf16(pf0, vf0,
                                                                    acc[t][j], 0, 0, 0);
                acc[t][j] = __builtin_amdgcn_mfma_f32_16x16x32_bf16(pf1, vf1,
                                                                    acc[t][j], 0, 0, 0);
            }
        }
    }

#pragma unroll
    for (int t = 0; t < 2; ++t) {
        float inv[4];
#pragma unroll
        for (int r = 0; r < 4; ++r) {
            float l = lsum[t][r];
#pragma unroll
            for (int off = 1; off < 16; off <<= 1) l += __shfl_xor(l, off, 16);
            inv[r] = 1.f / l;
        }
        const long orow = (long)b * 1024 + qbase + t * 16 + quad * 4;
#pragma unroll
        for (int j = 0; j < 4; ++j)
#pragma unroll
            for (int r = 0; r < 4; ++r)
                Out[(orow + r) * 1024 + h * 64 + j * 16 + lq] =
                    f2bf_fast(acc[t][j][r] * inv[r]);
    }
}

// ---------------------------------------------------------------------------
extern "C" void kernel_launch(void* const* d_in, const int* in_sizes, int n_in,
                              void* d_out, int out_size, void* d_ws, size_t ws_size,
                              hipStream_t stream) {
    const float* we        = (const float*)d_in[0];
    const int*   amask     = (const int*)d_in[1];
    const int*   span_b    = (const int*)d_in[2];
    const int*   span_s    = (const int*)d_in[3];
    const int*   span_t    = (const int*)d_in[4];
    const float* tag_emb   = (const float*)d_in[5];
    const float* gate_w    = (const float*)d_in[6];
    const float* gate_b    = (const float*)d_in[7];
    const float* attn_ln_g = (const float*)d_in[8];
    const float* attn_ln_b = (const float*)d_in[9];
    const float* in_proj_w = (const float*)d_in[10];
    const float* in_proj_b = (const float*)d_in[11];
    const float* out_proj_w= (const float*)d_in[12];
    const float* out_proj_b= (const float*)d_in[13];
    const float* enc1_g    = (const float*)d_in[14];
    const float* enc1_b    = (const float*)d_in[15];
    const float* lin1_w    = (const float*)d_in[16];
    const float* lin1_b    = (const float*)d_in[17];
    const float* lin2_w    = (const float*)d_in[18];
    const float* lin2_b    = (const float*)d_in[19];
    const float* enc2_g    = (const float*)d_in[20];
    const float* enc2_b    = (const float*)d_in[21];
    float* out = (float*)d_out;  // also fp32 scratch (out_pre/h1/h2)

    char* ws = (char*)d_ws;
    size_t off = 0;
    auto alloc = [&](size_t bytes) {
        void* p = ws + off;
        off += (bytes + 255) & ~(size_t)255;
        return p;
    };
    const size_t MT = 8192;
    u16* oe_bf   = (u16*)alloc(MT * 1024 * 2);
    u16* ax_bf   = (u16*)alloc(MT * 1024 * 2);
    char* region = (char*)alloc((size_t)67108864);             // qkv+vt | ff1
    u16* qkv_bf  = (u16*)region;
    u16* vt_bf   = (u16*)(region + (size_t)MT * 3072 * 2);
    u16* ff1_bf  = (u16*)region;
    u16* wb_inproj  = (u16*)alloc((size_t)3072 * 1024 * 2);
    u16* wb_outproj = (u16*)alloc((size_t)1024 * 1024 * 2);
    u16* wb_lin1    = (u16*)alloc((size_t)4096 * 1024 * 2);
    u16* wb_lin2    = (u16*)alloc((size_t)1024 * 4096 * 2);

    hipMemcpyAsync(out, we, MT * 1024 * 4, hipMemcpyDeviceToDevice, stream);
    f2bf_kernel<<<3072, 256, 0, stream>>>(in_proj_w, wb_inproj, 3072 * 1024 / 4);
    f2bf_kernel<<<1024, 256, 0, stream>>>(out_proj_w, wb_outproj, 1024 * 1024 / 4);
    f2bf_kernel<<<4096, 256, 0, stream>>>(lin1_w, wb_lin1, 4096 * 1024 / 4);
    f2bf_kernel<<<4096, 256, 0, stream>>>(lin2_w, wb_lin2, 1024 * 4096 / 4);
    span_kernel<<<16384, 256, 0, stream>>>(we, span_b, span_s, span_t, tag_emb,
                                           gate_w, gate_b, out);
    ln_kernel<false, true, false><<<8192, 256, 0, stream>>>(
        out, attn_ln_g, attn_ln_b, 1e-12f, nullptr, oe_bf, nullptr);
    dim3 g1(64, 24);
    gemm_nt<true, false, false><<<g1, 256, 0, stream>>>(oe_bf, wb_inproj, in_proj_b,
                                                        nullptr, qkv_bf, 3072, 1024);
    vtrans_kernel<<<2048, 256, 0, stream>>>(qkv_bf, vt_bf);
    attn_kernel<<<1024, 256, 0, stream>>>(qkv_bf, vt_bf, amask, ax_bf);
    dim3 g2(64, 8);
    gemm_nt<false, false, true><<<g2, 256, 0, stream>>>(ax_bf, wb_outproj, out_proj_b,
                                                        oe_bf, out, 1024, 1024);
    ln_kernel<false, true, false><<<8192, 256, 0, stream>>>(
        out, enc1_g, enc1_b, 1e-5f, nullptr, ax_bf, nullptr);
    dim3 g3(64, 32);
    gemm_nt<true, true, false><<<g3, 256, 0, stream>>>(ax_bf, wb_lin1, lin1_b,
                                                       nullptr, ff1_bf, 4096, 1024);
    gemm_nt<false, false, true><<<g2, 256, 0, stream>>>(ff1_bf, wb_lin2, lin2_b,
                                                        ax_bf, out, 1024, 4096);
    ln_kernel<true, false, true><<<8192, 256, 0, stream>>>(
        out, enc2_g, enc2_b, 1e-5f, out, nullptr, oe_bf);
}

// Round 5
// 542.681 us; speedup vs baseline: 1.3157x; 1.3157x over previous
//
#include <hip/hip_runtime.h>

#define DEV __device__ __forceinline__

typedef short bf16x8 __attribute__((ext_vector_type(8)));
typedef float f32x4 __attribute__((ext_vector_type(4)));
typedef unsigned short u16;
typedef unsigned int u32;

typedef __attribute__((address_space(3))) void lds_void;
typedef __attribute__((address_space(1))) void gbl_void;

DEV void async_copy16(void* lds_dst, const void* g_src) {
    __builtin_amdgcn_global_load_lds((gbl_void*)g_src, (lds_void*)lds_dst, 16, 0, 0);
}

DEV u16 f2bf(float x) {
    u32 u = __float_as_uint(x);
    return (u16)((u + 0x7fffu + ((u >> 16) & 1u)) >> 16);
}
DEV u16 f2bf_fast(float x) {  // x >= 0, finite
    return (u16)((__float_as_uint(x) + 0x8000u) >> 16);
}
DEV float bf2f(u16 v) { return __uint_as_float(((u32)v) << 16); }

// ---------------------------------------------------------------------------
// fp32 -> bf16 conversion (vectorized by 4)
// ---------------------------------------------------------------------------
__global__ __launch_bounds__(256) void f2bf_kernel(const float* __restrict__ src,
                                                   u16* __restrict__ dst, int n4) {
    const int i = blockIdx.x * 256 + threadIdx.x;
    if (i < n4) {
        const float4 v = ((const float4*)src)[i];
        ushort4 o;
        o.x = f2bf(v.x); o.y = f2bf(v.y); o.z = f2bf(v.z); o.w = f2bf(v.w);
        ((ushort4*)dst)[i] = o;
    }
}

// ---------------------------------------------------------------------------
// Span scatter: RoPE row -> gate dot -> atomicAdd coef*tag_emb into out_pre
// ---------------------------------------------------------------------------
__global__ __launch_bounds__(256) void span_kernel(
    const float* __restrict__ we, const int* __restrict__ sb,
    const int* __restrict__ ss, const int* __restrict__ stg,
    const float* __restrict__ tag_emb, const float* __restrict__ gate_w,
    const float* __restrict__ gate_b, float* __restrict__ out_pre) {
    __shared__ float red[4];
    const int n = blockIdx.x >> 5;
    const int l = blockIdx.x & 31;
    const int t = threadIdx.x;
    const int b = sb[n];
    const int s = ss[n] + l;
    const int tag = stg[n];
    const long base = ((long)b * 1024 + s) * 1024;
    float dot = 0.f;
#pragma unroll
    for (int pp = 0; pp < 2; ++pp) {
        const int p = t + pp * 256;
        const float e1 = we[base + 2 * p];
        const float e2 = we[base + 2 * p + 1];
        const float inv = exp2f((float)p * (-13.287712379549449f / 512.0f));
        const float ang = (float)s * inv;
        const float sa = sinf(ang), ca = cosf(ang);
        const float r1 = e1 * ca - e2 * sa;
        const float r2 = e1 * sa + e2 * ca;
        dot += r1 * gate_w[2 * p] + r2 * gate_w[2 * p + 1];
    }
#pragma unroll
    for (int off = 32; off > 0; off >>= 1) dot += __shfl_xor(dot, off, 64);
    if ((t & 63) == 0) red[t >> 6] = dot;
    __syncthreads();
    const float z = red[0] + red[1] + red[2] + red[3] + gate_b[0];
    const float gate = 0.25f + 0.5f / (1.f + __expf(-z));
    const float coef = gate * 16.f;
    const float* te = tag_emb + (long)tag * 1024;
#pragma unroll
    for (int c = 0; c < 4; ++c) {
        const int d = t + c * 256;
        atomicAdd(&out_pre[base + d], coef * te[d]);
    }
}

// ---------------------------------------------------------------------------
// LayerNorm over D=1024, one block per row.
// ---------------------------------------------------------------------------
template <bool WRITE_F32, bool WRITE_BF, bool FINAL>
__global__ __launch_bounds__(256) void ln_kernel(
    const float* __restrict__ X, const float* __restrict__ g,
    const float* __restrict__ bta, float eps, float* __restrict__ Yf,
    u16* __restrict__ Ybf, const u16* __restrict__ addend) {
    __shared__ float red[8];
    const long row = blockIdx.x;
    const int t = threadIdx.x;
    const float4 x = ((const float4*)(X + row * 1024))[t];
    float s = x.x + x.y + x.z + x.w;
#pragma unroll
    for (int off = 32; off > 0; off >>= 1) s += __shfl_xor(s, off, 64);
    if ((t & 63) == 0) red[t >> 6] = s;
    __syncthreads();
    const float mean = (red[0] + red[1] + red[2] + red[3]) * (1.f / 1024.f);
    float4 dx;
    dx.x = x.x - mean; dx.y = x.y - mean; dx.z = x.z - mean; dx.w = x.w - mean;
    float ss = dx.x * dx.x + dx.y * dx.y + dx.z * dx.z + dx.w * dx.w;
#pragma unroll
    for (int off = 32; off > 0; off >>= 1) ss += __shfl_xor(ss, off, 64);
    if ((t & 63) == 0) red[4 + (t >> 6)] = ss;
    __syncthreads();
    const float var = (red[4] + red[5] + red[6] + red[7]) * (1.f / 1024.f);
    const float rstd = rsqrtf(var + eps);
    const float4 gv = ((const float4*)g)[t];
    const float4 bv = ((const float4*)bta)[t];
    float4 y;
    y.x = dx.x * rstd * gv.x + bv.x;
    y.y = dx.y * rstd * gv.y + bv.y;
    y.z = dx.z * rstd * gv.z + bv.z;
    y.w = dx.w * rstd * gv.w + bv.w;
    if (FINAL) {
        const ushort4 a = ((const ushort4*)(addend + row * 1024))[t];
        y.x += bf2f(a.x); y.y += bf2f(a.y); y.z += bf2f(a.z); y.w += bf2f(a.w);
    }
    if (WRITE_F32) ((float4*)(Yf + row * 1024))[t] = y;
    if (WRITE_BF) {
        ushort4 o;
        o.x = f2bf(y.x); o.y = f2bf(y.y); o.z = f2bf(y.z); o.w = f2bf(y.w);
        ((ushort4*)(Ybf + row * 1024))[t] = o;
    }
}

// ---------------------------------------------------------------------------
// NT GEMM v3: round-3 structure (16x16x32 MFMA, 4x4 acc/wave, 128x128 tile)
// with BK=64 (half the barriers) and XOR slot-swizzled LDS image.
// Staging: chunk X (c*256+tid, c=0..3) stages row 32c+(tid>>3), LDS slot
// (tid&7); SOURCE k-chunk = (tid&7) ^ (row&7). 8 lanes cover one row's
// 128B contiguous (permuted within line -> same coalescing).
// Fragment read: row r, global k-quad g=ks*4+quad at LDS slot g^(r&7):
// dword-bank = slot*4+d, slot = const^(lq&7) -> uniform 2 lanes/bank group
// = conflict-free (m136).
// ---------------------------------------------------------------------------
template <bool OUT_BF16, bool RELU, bool HAS_RES>
__global__ __launch_bounds__(256, 2) void gemm_nt(
    const u16* __restrict__ A, const u16* __restrict__ B,
    const float* __restrict__ bias, const u16* __restrict__ res,
    void* __restrict__ Cout, int N, int K) {
    __shared__ u16 Al[8192];   // 128 rows x 64 k = 16 KB
    __shared__ u16 Bl[8192];
    const int tid = threadIdx.x;
    const int wave = tid >> 6;
    const int lane = tid & 63;
    const int quad = lane >> 4;
    const int lq = lane & 15;
    const int wm = wave >> 1;
    const int wn = wave & 1;
    const long rowBase = (long)blockIdx.x * 128;
    const long colBase = (long)blockIdx.y * 128;

    f32x4 acc[4][4];
    const f32x4 fzero = {0.f, 0.f, 0.f, 0.f};
#pragma unroll
    for (int i = 0; i < 4; ++i)
#pragma unroll
        for (int j = 0; j < 4; ++j) acc[i][j] = fzero;

    // staging addresses: row rX = tid>>3 (+32c), source k-chunk p^(rX&7)
    const int rX = tid >> 3;
    const int pX = (tid & 7) ^ (rX & 7);
    const u16* gA = A + (rowBase + rX) * (long)K + pX * 8;
    const u16* gB = B + (colBase + rX) * (long)K + pX * 8;
    u16* ldsA = Al + wave * 512;   // chunk c adds c*2048 (u16)
    u16* ldsB = Bl + wave * 512;

    for (int kt = 0; kt < K; kt += 64) {
        __syncthreads();
#pragma unroll
        for (int c = 0; c < 4; ++c) {
            async_copy16(ldsA + c * 2048, gA + (long)c * 32 * K + kt);
            async_copy16(ldsB + c * 2048, gB + (long)c * 32 * K + kt);
        }
        __syncthreads();
#pragma unroll
        for (int ks = 0; ks < 2; ++ks) {
            bf16x8 af[4], bfr[4];
#pragma unroll
            for (int i = 0; i < 4; ++i) {
                const int r = wm * 64 + i * 16 + lq;
                af[i] = *(const bf16x8*)&Al[r * 64 + (((ks * 4 + quad) ^ (lq & 7)) * 8)];
            }
#pragma unroll
            for (int j = 0; j < 4; ++j) {
                const int r = wn * 64 + j * 16 + lq;
                bfr[j] = *(const bf16x8*)&Bl[r * 64 + (((ks * 4 + quad) ^ (lq & 7)) * 8)];
            }
#pragma unroll
            for (int i = 0; i < 4; ++i)
#pragma unroll
                for (int j = 0; j < 4; ++j)
                    acc[i][j] = __builtin_amdgcn_mfma_f32_16x16x32_bf16(
                        af[i], bfr[j], acc[i][j], 0, 0, 0);
        }
    }

    float biasv[4];
#pragma unroll
    for (int j = 0; j < 4; ++j) biasv[j] = bias[colBase + wn * 64 + j * 16 + lq];
#pragma unroll
    for (int i = 0; i < 4; ++i) {
        const long grow = rowBase + wm * 64 + i * 16 + quad * 4;
#pragma unroll
        for (int j = 0; j < 4; ++j) {
            const long gcol = colBase + wn * 64 + j * 16 + lq;
#pragma unroll
            for (int r = 0; r < 4; ++r) {
                float v = acc[i][j][r] + biasv[j];
                if (RELU) v = fmaxf(v, 0.f);
                if (HAS_RES) v += bf2f(res[(grow + r) * N + gcol]);
                if (OUT_BF16)
                    ((u16*)Cout)[(grow + r) * N + gcol] = f2bf(v);
                else
                    ((float*)Cout)[(grow + r) * N + gcol] = v;
            }
        }
    }
}

// ---------------------------------------------------------------------------
// V transpose: Vt[b,h,d,s] (bf16) <- QKV[(b*S+s)*3072 + 2048 + h*64 + d]
// ---------------------------------------------------------------------------
__global__ __launch_bounds__(256) void vtrans_kernel(const u16* __restrict__ QKV,
                                                     u16* __restrict__ Vt) {
    __shared__ u16 tile[64][72];
    const int bid = blockIdx.x;
    const int st = bid & 15;
    const int h = (bid >> 4) & 15;
    const int b = bid >> 8;
    const int t = threadIdx.x;
    const int sl = t >> 2;
    const int dc = (t & 3) * 16;
    const u16* src = QKV + ((long)(b * 1024 + st * 64 + sl)) * 3072 + 2048 + h * 64 + dc;
    *(uint4*)&tile[sl][dc] = *(const uint4*)src;
    *(uint4*)&tile[sl][dc + 8] = *(const uint4*)(src + 8);
    __syncthreads();
    const int dl = t >> 2;
    const int sc = (t & 3) * 16;
    union { u16 u[16]; uint4 q[2]; } tmp;
#pragma unroll
    for (int i = 0; i < 16; ++i) tmp.u[i] = tile[sc + i][dl];
    u16* dst = Vt + ((long)(b * 16 + h) * 64 + dl) * 1024 + st * 64 + sc;
    *(uint4*)dst = tmp.q[0];
    *(uint4*)(dst + 8) = tmp.q[1];
}

// ---------------------------------------------------------------------------
// Flash attention (round-3 version, unchanged).
// ---------------------------------------------------------------------------
__global__ __launch_bounds__(256, 4) void attn_kernel(
    const u16* __restrict__ QKV, const u16* __restrict__ Vt,
    const int* __restrict__ mask, u16* __restrict__ Out) {
    __shared__ u16 KL[4096];
    __shared__ u16 VL[4096];
    __shared__ u16 PL[4][16 * 72];
    const int tid = threadIdx.x;
    const int wid = tid >> 6;
    const int lane = tid & 63;
    const int quad = lane >> 4;
    const int lq = lane & 15;
    const int slot0 = quad ^ (lq & 7);
    const int slot1 = slot0 ^ 4;

    const int bid = blockIdx.x;
    const int qb = bid & 7;
    const int h = (bid >> 3) & 15;
    const int b = bid >> 7;
    const int qbase = qb * 128 + wid * 32;

    bf16x8 aq[2][2];
#pragma unroll
    for (int t = 0; t < 2; ++t) {
        const u16* qp = QKV + ((long)(b * 1024 + qbase + t * 16 + lq)) * 3072 +
                        h * 64 + quad * 8;
        aq[t][0] = *(const bf16x8*)qp;
        aq[t][1] = *(const bf16x8*)(qp + 32);
    }

    const int c0 = tid, c1 = 256 + tid;
    const int r0 = c0 >> 3, j0 = (c0 & 7) ^ (r0 & 7);
    const int r1 = c1 >> 3, j1 = (c1 & 7) ^ (r1 & 7);
    const u16* srcK0 = QKV + ((long)(b * 1024 + r0)) * 3072 + 1024 + h * 64 + j0 * 8;
    const u16* srcK1 = QKV + ((long)(b * 1024 + r1)) * 3072 + 1024 + h * 64 + j1 * 8;
    const u16* srcV0 = Vt + ((long)(b * 16 + h) * 64 + r0) * 1024 + j0 * 8;
    const u16* srcV1 = Vt + ((long)(b * 16 + h) * 64 + r1) * 1024 + j1 * 8;
    u16* ldsK0 = KL + wid * 512;
    u16* ldsK1 = KL + 2048 + wid * 512;
    u16* ldsV0 = VL + wid * 512;
    u16* ldsV1 = VL + 2048 + wid * 512;

    const f32x4 fzero = {0.f, 0.f, 0.f, 0.f};
    f32x4 acc[2][4];
#pragma unroll
    for (int t = 0; t < 2; ++t)
#pragma unroll
        for (int j = 0; j < 4; ++j) acc[t][j] = fzero;
    float lsum[2][4] = {{0.f, 0.f, 0.f, 0.f}, {0.f, 0.f, 0.f, 0.f}};
    u16* myP = PL[wid];
    const int* mrow = mask + b * 1024;

    for (int kt = 0; kt < 1024; kt += 64) {
        __syncthreads();
        async_copy16(ldsK0, srcK0 + (long)kt * 3072);
        async_copy16(ldsK1, srcK1 + (long)kt * 3072);
        async_copy16(ldsV0, srcV0 + kt);
        async_copy16(ldsV1, srcV1 + kt);
        __syncthreads();

        bf16x8 kf0[4], kf1[4];
#pragma unroll
        for (int ct = 0; ct < 4; ++ct) {
            const int rowb = (ct * 16 + lq) * 64;
            kf0[ct] = *(const bf16x8*)&KL[rowb + slot0 * 8];
            kf1[ct] = *(const bf16x8*)&KL[rowb + slot1 * 8];
        }
        float mw[4];
#pragma unroll
        for (int ct = 0; ct < 4; ++ct) mw[ct] = mrow[kt + ct * 16 + lq] ? 1.f : 0.f;

#pragma unroll
        for (int t = 0; t < 2; ++t) {
            f32x4 s[4];
#pragma unroll
            for (int ct = 0; ct < 4; ++ct) {
                s[ct] = __builtin_amdgcn_mfma_f32_16x16x32_bf16(aq[t][0], kf0[ct],
                                                                fzero, 0, 0, 0);
                s[ct] = __builtin_amdgcn_mfma_f32_16x16x32_bf16(aq[t][1], kf1[ct],
                                                                s[ct], 0, 0, 0);
            }
            asm volatile("s_waitcnt lgkmcnt(0)" ::: "memory");
#pragma unroll
            for (int ct = 0; ct < 4; ++ct)
#pragma unroll
                for (int r = 0; r < 4; ++r) {
                    const float p = mw[ct] * __expf(s[ct][r] * 0.125f);
                    lsum[t][r] += p;
                    myP[(quad * 4 + r) * 72 + ct * 16 + lq] = f2bf_fast(p);
                }
            asm volatile("s_waitcnt lgkmcnt(0)" ::: "memory");
            const bf16x8 pf0 = *(const bf16x8*)&myP[lq * 72 + quad * 8];
            const bf16x8 pf1 = *(const bf16x8*)&myP[lq * 72 + 32 + quad * 8];
#pragma unroll
            for (int j = 0; j < 4; ++j) {
                const int rowb = (j * 16 + lq) * 64;
                const bf16x8 vf0 = *(const bf16x8*)&VL[rowb + slot0 * 8];
                const bf16x8 vf1 = *(const bf16x8*)&VL[rowb + slot1 * 8];
                acc[t][j] = __builtin_amdgcn_mfma_f32_16x16x32_bf16(pf0, vf0,
                                                                    acc[t][j], 0, 0, 0);
                acc[t][j] = __builtin_amdgcn_mfma_f32_16x16x32_bf16(pf1, vf1,
                                                                    acc[t][j], 0, 0, 0);
            }
        }
    }

#pragma unroll
    for (int t = 0; t < 2; ++t) {
        float inv[4];
#pragma unroll
        for (int r = 0; r < 4; ++r) {
            float l = lsum[t][r];
#pragma unroll
            for (int off = 1; off < 16; off <<= 1) l += __shfl_xor(l, off, 16);
            inv[r] = 1.f / l;
        }
        const long orow = (long)b * 1024 + qbase + t * 16 + quad * 4;
#pragma unroll
        for (int j = 0; j < 4; ++j)
#pragma unroll
            for (int r = 0; r < 4; ++r)
                Out[(orow + r) * 1024 + h * 64 + j * 16 + lq] =
                    f2bf_fast(acc[t][j][r] * inv[r]);
    }
}

// ---------------------------------------------------------------------------
extern "C" void kernel_launch(void* const* d_in, const int* in_sizes, int n_in,
                              void* d_out, int out_size, void* d_ws, size_t ws_size,
                              hipStream_t stream) {
    const float* we        = (const float*)d_in[0];
    const int*   amask     = (const int*)d_in[1];
    const int*   span_b    = (const int*)d_in[2];
    const int*   span_s    = (const int*)d_in[3];
    const int*   span_t    = (const int*)d_in[4];
    const float* tag_emb   = (const float*)d_in[5];
    const float* gate_w    = (const float*)d_in[6];
    const float* gate_b    = (const float*)d_in[7];
    const float* attn_ln_g = (const float*)d_in[8];
    const float* attn_ln_b = (const float*)d_in[9];
    const float* in_proj_w = (const float*)d_in[10];
    const float* in_proj_b = (const float*)d_in[11];
    const float* out_proj_w= (const float*)d_in[12];
    const float* out_proj_b= (const float*)d_in[13];
    const float* enc1_g    = (const float*)d_in[14];
    const float* enc1_b    = (const float*)d_in[15];
    const float* lin1_w    = (const float*)d_in[16];
    const float* lin1_b    = (const float*)d_in[17];
    const float* lin2_w    = (const float*)d_in[18];
    const float* lin2_b    = (const float*)d_in[19];
    const float* enc2_g    = (const float*)d_in[20];
    const float* enc2_b    = (const float*)d_in[21];
    float* out = (float*)d_out;  // also fp32 scratch (out_pre/h1/h2)

    char* ws = (char*)d_ws;
    size_t off = 0;
    auto alloc = [&](size_t bytes) {
        void* p = ws + off;
        off += (bytes + 255) & ~(size_t)255;
        return p;
    };
    const size_t MT = 8192;
    u16* oe_bf   = (u16*)alloc(MT * 1024 * 2);
    u16* ax_bf   = (u16*)alloc(MT * 1024 * 2);
    char* region = (char*)alloc((size_t)67108864);             // qkv+vt | ff1
    u16* qkv_bf  = (u16*)region;
    u16* vt_bf   = (u16*)(region + (size_t)MT * 3072 * 2);
    u16* ff1_bf  = (u16*)region;
    u16* wb_inproj  = (u16*)alloc((size_t)3072 * 1024 * 2);
    u16* wb_outproj = (u16*)alloc((size_t)1024 * 1024 * 2);
    u16* wb_lin1    = (u16*)alloc((size_t)4096 * 1024 * 2);
    u16* wb_lin2    = (u16*)alloc((size_t)1024 * 4096 * 2);

    hipMemcpyAsync(out, we, MT * 1024 * 4, hipMemcpyDeviceToDevice, stream);
    f2bf_kernel<<<3072, 256, 0, stream>>>(in_proj_w, wb_inproj, 3072 * 1024 / 4);
    f2bf_kernel<<<1024, 256, 0, stream>>>(out_proj_w, wb_outproj, 1024 * 1024 / 4);
    f2bf_kernel<<<4096, 256, 0, stream>>>(lin1_w, wb_lin1, 4096 * 1024 / 4);
    f2bf_kernel<<<4096, 256, 0, stream>>>(lin2_w, wb_lin2, 1024 * 4096 / 4);
    span_kernel<<<16384, 256, 0, stream>>>(we, span_b, span_s, span_t, tag_emb,
                                           gate_w, gate_b, out);
    ln_kernel<false, true, false><<<8192, 256, 0, stream>>>(
        out, attn_ln_g, attn_ln_b, 1e-12f, nullptr, oe_bf, nullptr);
    dim3 g1(64, 24);
    gemm_nt<true, false, false><<<g1, 256, 0, stream>>>(oe_bf, wb_inproj, in_proj_b,
                                                        nullptr, qkv_bf, 3072, 1024);
    vtrans_kernel<<<2048, 256, 0, stream>>>(qkv_bf, vt_bf);
    attn_kernel<<<1024, 256, 0, stream>>>(qkv_bf, vt_bf, amask, ax_bf);
    dim3 g2(64, 8);
    gemm_nt<false, false, true><<<g2, 256, 0, stream>>>(ax_bf, wb_outproj, out_proj_b,
                                                        oe_bf, out, 1024, 1024);
    ln_kernel<false, true, false><<<8192, 256, 0, stream>>>(
        out, enc1_g, enc1_b, 1e-5f, nullptr, ax_bf, nullptr);
    dim3 g3(64, 32);
    gemm_nt<true, true, false><<<g3, 256, 0, stream>>>(ax_bf, wb_lin1, lin1_b,
                                                       nullptr, ff1_bf, 4096, 1024);
    gemm_nt<false, false, true><<<g2, 256, 0, stream>>>(ff1_bf, wb_lin2, lin2_b,
                                                        ax_bf, out, 1024, 4096);
    ln_kernel<true, false, true><<<8192, 256, 0, stream>>>(
        out, enc2_g, enc2_b, 1e-5f, out, nullptr, oe_bf);
}